// Round 23
// baseline (145.015 us; speedup 1.0000x reference)
//
#include <hip/hip_runtime.h>

// MLPNodeLink: out[i,j] = relu(relu(relu([V1_i|V2_j]@W1+b1)@W2+b2)@W3+b3)
// h1[i,j] = relu(A[i] + B[j]), A=V1@W1[:128]+b1, B=V2@W1[128:]
// Round 23: r22 + overlapped second-half fill. sA split into two 64KB
// k-halves; prologue fills half0; half1's fill interleaved into half0's
// 16 compute steps (even s: 1 uint4 Bpb load; odd s: pack+ds_write; 4 regs
// in flight, sched_barrier(0) pins loads). One extra barrier at half switch.
// bfr ring 5->3 dist-2 (depth null per r13) buys register headroom:
// ~104 VGPR + 128 AGPR = 232 <= 256. K-loop/epilogue otherwise r22.

typedef short bf16x8 __attribute__((ext_vector_type(8)));
typedef float f32x16 __attribute__((ext_vector_type(16)));

#define NROW 512
#define FDIM 128
#define HDIM 512

__device__ __forceinline__ unsigned int pk2(float x, float y) {
  unsigned int r;
  asm("v_cvt_pk_bf16_f32 %0, %1, %2" : "=v"(r) : "v"(x), "v"(y));
  return r;
}
__device__ __forceinline__ unsigned short f2bf(float x) {  // RTNE
  unsigned int u = __builtin_bit_cast(unsigned int, x);
  u += 0x7fffu + ((u >> 16) & 1u);
  return (unsigned short)(u >> 16);
}
__device__ __forceinline__ float bflo(unsigned int u) {
  return __builtin_bit_cast(float, u << 16);
}
__device__ __forceinline__ float bfhi(unsigned int u) {
  return __builtin_bit_cast(float, u & 0xffff0000u);
}
__device__ __forceinline__ uint4 packrow(const float4& a0, const float4& a1, const uint4& ub) {
  return make_uint4(pk2(fmaxf(a0.x + bflo(ub.x), 0.f), fmaxf(a0.y + bfhi(ub.x), 0.f)),
                    pk2(fmaxf(a0.z + bflo(ub.y), 0.f), fmaxf(a0.w + bfhi(ub.y), 0.f)),
                    pk2(fmaxf(a1.x + bflo(ub.z), 0.f), fmaxf(a1.y + bfhi(ub.z), 0.f)),
                    pk2(fmaxf(a1.z + bflo(ub.w), 0.f), fmaxf(a1.w + bfhi(ub.w), 0.f)));
}

// ---- fused prep: blocks 0..255 -> A/B rows; 256..383 -> W2 retile ----
__global__ __launch_bounds__(256) void prep_fused(
    const float* __restrict__ V1, const float* __restrict__ V2,
    const float* __restrict__ W1, const float* __restrict__ b1,
    const float* __restrict__ W2, float* __restrict__ Ap,
    unsigned short* __restrict__ Bpb, unsigned short* __restrict__ W2T) {
  const int b = blockIdx.x;
  const int t = threadIdx.x;
  if (b >= 256) {  // ---- W2 retile role ----
    const int o = (b - 256) * 256 + t;
    const int kc = o >> 9;
    const int n = o & 511;
    unsigned int u[4];
#pragma unroll
    for (int e2 = 0; e2 < 4; ++e2)
      u[e2] = pk2(W2[(kc * 8 + 2 * e2) * HDIM + n], W2[(kc * 8 + 2 * e2 + 1) * HDIM + n]);
    *(uint4*)(W2T + (size_t)o * 8) = make_uint4(u[0], u[1], u[2], u[3]);
    return;
  }
  __shared__ float sv[4 * FDIM];
  const bool isB = b >= 128;
  const int r0 = (b & 127) * 4;
  const float* V = isB ? V2 : V1;
  const float* W = W1 + (isB ? FDIM * HDIM : 0);
  for (int idx = t; idx < 4 * FDIM; idx += 256) sv[idx] = V[r0 * FDIM + idx];
  __syncthreads();
  float s[4][2] = {};
  for (int k = 0; k < FDIM; ++k) {
    const float w0 = W[k * HDIM + t];
    const float w1 = W[k * HDIM + t + 256];
#pragma unroll
    for (int r = 0; r < 4; ++r) {
      const float v = sv[r * FDIM + k];
      s[r][0] += v * w0;
      s[r][1] += v * w1;
    }
  }
  if (isB) {
#pragma unroll
    for (int r = 0; r < 4; ++r) {
      Bpb[(r0 + r) * HDIM + t] = f2bf(s[r][0]);
      Bpb[(r0 + r) * HDIM + t + 256] = f2bf(s[r][1]);
    }
  } else {
    const float bb0 = b1[t];
    const float bb1 = b1[t + 256];
#pragma unroll
    for (int r = 0; r < 4; ++r) {
      Ap[(r0 + r) * HDIM + t] = s[r][0] + bb0;
      Ap[(r0 + r) * HDIM + t + 256] = s[r][1] + bb1;
    }
  }
}

// ---- main: 128 pair-rows x 512 cols per block; 8 waves; wave = 128x64
// (4mt x 2nt of 32x32). sA = two 64KB k-halves, rows 512B, 5-bit XOR
// swizzle. Half0 compute interleaves half1 fill. af ring-2, bfr ring-3.
__global__ __launch_bounds__(512, 2) void mlp_main(
    const float* __restrict__ Ap, const unsigned short* __restrict__ Bpb,
    const unsigned short* __restrict__ W2T, const float* __restrict__ b2,
    const float* __restrict__ W3, const float* __restrict__ b3,
    float* __restrict__ out) {
  extern __shared__ char smem[];

  const int tid = threadIdx.x;
  const int wave = tid >> 6;
  const int lane = tid & 63;
  const int cl = lane & 31;  // frag row/col index (= row&31 for all mt)
  const int hi = lane >> 5;  // k-octet select
  const int fc = tid & 31;   // fill chunk within half (16B = 8 k)
  const int frs = tid >> 5;  // fill row-sub 0..15

  const int m0 = blockIdx.x * 128;
  const int i = m0 >> 9;
  const int j0 = m0 & 511;

  const char* bbase = (const char*)W2T + (((wave << 6) + cl) << 4) + (hi << 13);

  // bfr ring-3 prologue (before fill: L2 latency hides under fill VALU)
  bf16x8 af[2][4], bfr[3][2];
#pragma unroll
  for (int q = 0; q < 2; ++q) {
    const char* bp = bbase + ((size_t)q << 14);
    bfr[q][0] = *(const bf16x8*)(bp);
    bfr[q][1] = *(const bf16x8*)(bp + (1 << 9));
  }
  // hoisted epilogue weights
  float w30[2], w31[2], bb[2];
#pragma unroll
  for (int nt = 0; nt < 2; ++nt) {
    const int n = (wave << 6) + (nt << 5) + cl;
    w30[nt] = W3[2 * n];
    w31[nt] = W3[2 * n + 1];
    bb[nt] = b2[n];
  }
  const float bb3_0 = b3[0], bb3_1 = b3[1];

  // ---- prologue fill: half0 (k 0..255) -> sA0 ----
  {
    const float4 a0 = *(const float4*)(Ap + i * HDIM + fc * 8);
    const float4 a1 = *(const float4*)(Ap + i * HDIM + fc * 8 + 4);
#pragma unroll
    for (int it = 0; it < 8; ++it) {
      const int row = it * 16 + frs;
      const uint4 ub = *(const uint4*)(Bpb + (size_t)(j0 + row) * HDIM + fc * 8);
      *(uint4*)(smem + row * 512 + ((fc ^ (row & 31)) << 4)) = packrow(a0, a1, ub);
    }
  }
  // half1 A-row values (held through half0 compute; 8 regs)
  const float4 a0n = *(const float4*)(Ap + i * HDIM + 256 + fc * 8);
  const float4 a1n = *(const float4*)(Ap + i * HDIM + 256 + fc * 8 + 4);
  __syncthreads();

  f32x16 acc[4][2];
#pragma unroll
  for (int mt = 0; mt < 4; ++mt)
#pragma unroll
    for (int nt = 0; nt < 2; ++nt)
#pragma unroll
      for (int q = 0; q < 16; ++q) acc[mt][nt][q] = 0.f;

  // ---- half0 compute (global steps 0..15) + interleaved half1 fill ----
  {
    const char* abase = smem + cl * 512;  // mt at +mt*16384
    char* sA1 = smem + 65536;
    {
      const int off = (hi ^ cl) << 4;  // sl=0
#pragma unroll
      for (int mt = 0; mt < 4; ++mt) af[0][mt] = *(const bf16x8*)(abase + mt * 16384 + off);
    }
    uint4 ub;
    int frow = 0;
#pragma unroll
    for (int s = 0; s < 16; ++s) {
      const int cur = s & 1;
      if ((s & 1) == 0) {
        __builtin_amdgcn_sched_barrier(0);  // pin fill loads to their step
        frow = (s >> 1) * 16 + frs;
        ub = *(const uint4*)(Bpb + (size_t)(j0 + frow) * HDIM + 256 + fc * 8);
      } else {
        *(uint4*)(sA1 + frow * 512 + ((fc ^ (frow & 31)) << 4)) = packrow(a0n, a1n, ub);
      }
      if (s < 15) {
        const int off = (((((s + 1) << 1) | hi)) ^ cl) << 4;
#pragma unroll
        for (int mt = 0; mt < 4; ++mt)
          af[cur ^ 1][mt] = *(const bf16x8*)(abase + mt * 16384 + off);
      }
      {  // bfr prefetch dist-2
        const char* bp = bbase + ((size_t)(s + 2) << 14);
        bfr[(s + 2) % 3][0] = *(const bf16x8*)(bp);
        bfr[(s + 2) % 3][1] = *(const bf16x8*)(bp + (1 << 9));
      }
      __builtin_amdgcn_s_setprio(1);
#pragma unroll
      for (int nt = 0; nt < 2; ++nt)
#pragma unroll
        for (int mt = 0; mt < 4; ++mt)
          acc[mt][nt] = __builtin_amdgcn_mfma_f32_32x32x16_bf16(af[cur][mt], bfr[s % 3][nt],
                                                                acc[mt][nt], 0, 0, 0);
      __builtin_amdgcn_s_setprio(0);
    }
  }
  __syncthreads();  // half1 fill visible

  // ---- half1 compute (global steps 16..31), no fill ----
  {
    const char* abase = smem + 65536 + cl * 512;
    {
      const int off = (hi ^ cl) << 4;  // sl=0
#pragma unroll
      for (int mt = 0; mt < 4; ++mt) af[0][mt] = *(const bf16x8*)(abase + mt * 16384 + off);
    }
#pragma unroll
    for (int sl = 0; sl < 16; ++sl) {
      const int s = 16 + sl;
      const int cur = sl & 1;
      if (sl < 15) {
        const int off = (((((sl + 1) << 1) | hi)) ^ cl) << 4;
#pragma unroll
        for (int mt = 0; mt < 4; ++mt)
          af[cur ^ 1][mt] = *(const bf16x8*)(abase + mt * 16384 + off);
      }
      if (s < 30) {
        const char* bp = bbase + ((size_t)(s + 2) << 14);
        bfr[(s + 2) % 3][0] = *(const bf16x8*)(bp);
        bfr[(s + 2) % 3][1] = *(const bf16x8*)(bp + (1 << 9));
      }
      __builtin_amdgcn_s_setprio(1);
#pragma unroll
      for (int nt = 0; nt < 2; ++nt)
#pragma unroll
        for (int mt = 0; mt < 4; ++mt)
          acc[mt][nt] = __builtin_amdgcn_mfma_f32_32x32x16_bf16(af[cur][mt], bfr[s % 3][nt],
                                                                acc[mt][nt], 0, 0, 0);
      __builtin_amdgcn_s_setprio(0);
    }
  }
  __syncthreads();  // sA reads done; both 64KB halves reused below

  // ---- epilogue: 2 rounds; round r handles mt = 2r, 2r+1 in parallel ----
#pragma unroll
  for (int rnd = 0; rnd < 2; ++rnd) {
#pragma unroll
    for (int ml = 0; ml < 2; ++ml) {
      const int mt = rnd * 2 + ml;
      char* ebuf = smem + ml * 65536;  // [16 rp][256 slot][16B]
#pragma unroll
      for (int rp = 0; rp < 8; ++rp) {
        const int ra = 2 * rp;
        const float h0a = fmaxf(acc[mt][0][ra] + bb[0], 0.f);
        const float h1a = fmaxf(acc[mt][1][ra] + bb[1], 0.f);
        const float h0b = fmaxf(acc[mt][0][ra + 1] + bb[0], 0.f);
        const float h1b = fmaxf(acc[mt][1][ra + 1] + bb[1], 0.f);
        const float4 v =
            make_float4(h0a * w30[0] + h1a * w30[1], h0a * w31[0] + h1a * w31[1],
                        h0b * w30[0] + h1b * w30[1], h0b * w31[0] + h1b * w31[1]);
        const int rpi = ((ra & 3) + 8 * (ra >> 2) + 4 * hi) >> 1;
        *(float4*)(ebuf + rpi * 4096 + (((wave << 5) + cl) << 4)) = v;
      }
    }
    __syncthreads();
    {
      const int ml = tid >> 8;
      const int t2 = tid & 255;
      const int rpi = t2 >> 4;
      const int sub = t2 & 15;
      const char* ebuf = smem + ml * 65536;
      float4 s4 = make_float4(0.f, 0.f, 0.f, 0.f);
#pragma unroll
      for (int k = 0; k < 16; ++k) {
        const float4 v = *(const float4*)(ebuf + rpi * 4096 + ((sub + (k << 4)) << 4));
        s4.x += v.x; s4.y += v.y; s4.z += v.z; s4.w += v.w;
      }
#pragma unroll
      for (int d = 1; d < 16; d <<= 1) {
        s4.x += __shfl_xor(s4.x, d, 64);
        s4.y += __shfl_xor(s4.y, d, 64);
        s4.z += __shfl_xor(s4.z, d, 64);
        s4.w += __shfl_xor(s4.w, d, 64);
      }
      if (sub == 0) {
        const int rg = m0 + ((rnd * 2 + ml) << 5) + (rpi << 1);
        *(float4*)(out + rg * 2) =
            make_float4(fmaxf(s4.x + bb3_0, 0.f), fmaxf(s4.y + bb3_1, 0.f),
                        fmaxf(s4.z + bb3_0, 0.f), fmaxf(s4.w + bb3_1, 0.f));
      }
    }
    __syncthreads();
  }
}

extern "C" void kernel_launch(void* const* d_in, const int* in_sizes, int n_in,
                              void* d_out, int out_size, void* d_ws, size_t ws_size,
                              hipStream_t stream) {
  const float* V1 = (const float*)d_in[0];
  const float* V2 = (const float*)d_in[1];
  const float* W1 = (const float*)d_in[2];
  const float* b1 = (const float*)d_in[3];
  const float* W2 = (const float*)d_in[4];
  const float* b2 = (const float*)d_in[5];
  const float* W3 = (const float*)d_in[6];
  const float* b3 = (const float*)d_in[7];

  // ws layout: Ap (1MB f32) | Bpb (512KB bf16) | W2T (512KB bf16 tiled)
  float* Ap = (float*)d_ws;
  unsigned short* Bpb = (unsigned short*)(Ap + NROW * HDIM);
  unsigned short* W2T = Bpb + NROW * HDIM;

  const int smem_bytes = 131072;
  (void)hipFuncSetAttribute((const void*)mlp_main,
                            hipFuncAttributeMaxDynamicSharedMemorySize, smem_bytes);

  prep_fused<<<384, 256, 0, stream>>>(V1, V2, W1, b1, W2, Ap, Bpb, W2T);
  mlp_main<<<2048, 512, smem_bytes, stream>>>(Ap, Bpb, W2T, b2, W3, b3, (float*)d_out);
}